// Round 3
// baseline (385.732 us; speedup 1.0000x reference)
//
#include <hip/hip_runtime.h>
#include <hip/hip_bf16.h>

#define NN 100000
#define EE 1600000
#define NB 1563          // ceil(NN/64) dst-buckets of 64 nodes
#define NSUB 8           // sub-buffers (~XCD) for write locality
#define CAPS 240         // capacity per (sub,bucket); lambda=128
#define NBIN (EE / 256)  // 6250 bin blocks
#define NLIN ((NN + 63) / 64)  // 1563 lin1 blocks

// workspace byte offsets
#define OFF_CNT 0u                // NSUB*NB*4 = 50016
#define OFF_BUF 50176u            // NSUB*NB*CAPS*4 = 12003840
#define OFF_P   12054016u         // NN*64*2 = 12800000 (bf16)
#define OFF_Q   24854016u         // NN*64*2
// total 37654016 B ~= 35.9 MB

__device__ __forceinline__ ushort f2bf(float f) {
  unsigned u = __float_as_uint(f);
  unsigned r = (u + 0x7FFFu + ((u >> 16) & 1u)) >> 16;
  return (ushort)r;
}
__device__ __forceinline__ float bf2f(ushort h) {
  return __uint_as_float(((unsigned)h) << 16);
}
__device__ __forceinline__ unsigned pk2(float a, float b) {
  return (unsigned)f2bf(a) | ((unsigned)f2bf(b) << 16);
}

// ---------------- fat kernel: edge binning (blocks < NBIN) + lin1 -------------
// lin1: P = x@w1[:64], Qb = x@w1[64:] + b1   (bf16 outputs)
__launch_bounds__(256)
__global__ void k_pre(const int* __restrict__ ei, int* __restrict__ cnt,
                      unsigned* __restrict__ buf, const float* __restrict__ x,
                      const float* __restrict__ w1, const float* __restrict__ b1,
                      ushort* __restrict__ P, ushort* __restrict__ Qb) {
  __shared__ ushort w1s[128 * 64];   // bf16 weights, 16 KB
  __shared__ float xs[64 * 66];      // fp32 x tile, padded pitch 66
  int t = threadIdx.x;
  if (blockIdx.x < NBIN) {
    int i = blockIdx.x * 256 + t;
    int s = ei[i];
    int d = ei[EE + i];
    int b = d >> 6;
    int sub = blockIdx.x & (NSUB - 1);
    int pos = atomicAdd(&cnt[sub * NB + b], 1);
    if (pos < CAPS)
      buf[(sub * NB + b) * CAPS + pos] = (unsigned)s | ((unsigned)(d & 63) << 17);
    return;
  }
  int bid = blockIdx.x - NBIN;
  int base = bid * 64;
  // stage w1 -> bf16 LDS (4096 uints)
  #pragma unroll
  for (int i = 0; i < 16; ++i) {
    int j = t + i * 256;
    float2 v = *reinterpret_cast<const float2*>(&w1[2 * j]);
    reinterpret_cast<unsigned*>(w1s)[j] = pk2(v.x, v.y);
  }
  // stage x tile (fp32)
  #pragma unroll
  for (int i = 0; i < 4; ++i) {
    int idx4 = t + i * 256;
    int r = idx4 >> 4, c = idx4 & 15;
    int grow = base + r;
    float4 v = make_float4(0.f, 0.f, 0.f, 0.f);
    if (grow < NN) v = reinterpret_cast<const float4*>(x)[grow * 16 + c];
    float* p = &xs[r * 66 + c * 4];
    *reinterpret_cast<float2*>(p) = make_float2(v.x, v.y);
    *reinterpret_cast<float2*>(p + 2) = make_float2(v.z, v.w);
  }
  __syncthreads();
  int tr = t >> 4, tc = t & 15;
  int half = tc >> 3;           // 0 -> P, 1 -> Qb
  int c0 = (tc & 7) * 8;
  float acc[4][8];
  #pragma unroll
  for (int i = 0; i < 4; ++i)
    #pragma unroll
    for (int j = 0; j < 8; ++j) acc[i][j] = 0.f;
  #pragma unroll 4
  for (int k = 0; k < 64; ++k) {
    float a0 = xs[(4 * tr + 0) * 66 + k];
    float a1 = xs[(4 * tr + 1) * 66 + k];
    float a2 = xs[(4 * tr + 2) * 66 + k];
    float a3 = xs[(4 * tr + 3) * 66 + k];
    uint4 wv = *reinterpret_cast<const uint4*>(&w1s[(half * 64 + k) * 64 + c0]);
    float wf[8];
    wf[0] = bf2f((ushort)(wv.x & 0xFFFFu)); wf[1] = bf2f((ushort)(wv.x >> 16));
    wf[2] = bf2f((ushort)(wv.y & 0xFFFFu)); wf[3] = bf2f((ushort)(wv.y >> 16));
    wf[4] = bf2f((ushort)(wv.z & 0xFFFFu)); wf[5] = bf2f((ushort)(wv.z >> 16));
    wf[6] = bf2f((ushort)(wv.w & 0xFFFFu)); wf[7] = bf2f((ushort)(wv.w >> 16));
    #pragma unroll
    for (int j = 0; j < 8; ++j) {
      acc[0][j] = fmaf(a0, wf[j], acc[0][j]);
      acc[1][j] = fmaf(a1, wf[j], acc[1][j]);
      acc[2][j] = fmaf(a2, wf[j], acc[2][j]);
      acc[3][j] = fmaf(a3, wf[j], acc[3][j]);
    }
  }
  if (half) {
    #pragma unroll
    for (int j = 0; j < 8; ++j) {
      float bv = b1[c0 + j];
      #pragma unroll
      for (int i = 0; i < 4; ++i) acc[i][j] += bv;
    }
  }
  ushort* dstb = (half ? Qb : P);
  #pragma unroll
  for (int i = 0; i < 4; ++i) {
    int row = base + 4 * tr + i;
    if (row < NN) {
      uint4 o = make_uint4(pk2(acc[i][0], acc[i][1]), pk2(acc[i][2], acc[i][3]),
                           pk2(acc[i][4], acc[i][5]), pk2(acc[i][6], acc[i][7]));
      *reinterpret_cast<uint4*>(&dstb[row * 64 + c0]) = o;
    }
  }
}

// -------- fused: bucket sort + gather-aggregate + final GEMM -> out ----------
__launch_bounds__(256)
__global__ void k_aggfinal(const int* __restrict__ cnt, const unsigned* __restrict__ buf,
                           const unsigned* __restrict__ P32, const unsigned* __restrict__ Qb32,
                           const float* __restrict__ x, const float* __restrict__ w2,
                           const float* __restrict__ b2, const float* __restrict__ wsw,
                           const float* __restrict__ bs, float* __restrict__ out) {
  __shared__ float ts[64 * 66];             // u tile / x tile (16.9 KB); aliases raw
  __shared__ unsigned sorted[NSUB * CAPS];  // 7.7 KB
  __shared__ ushort Wss[128 * 64];          // bf16 [w2; ws], 16 KB
  __shared__ int hist[64], offs[64], starts[64];
  unsigned* raw = reinterpret_cast<unsigned*>(ts);  // phase-A only
  int b = blockIdx.x;
  int t = threadIdx.x;
  if (t < 64) hist[t] = 0;
  __syncthreads();
  // ---- phase A: gather bucket entries, histogram, sort by local dst ----
  int tot = 0;
  #pragma unroll
  for (int s = 0; s < NSUB; ++s) {
    int c = min(cnt[s * NB + b], CAPS);
    for (int i = t; i < c; i += 256) {
      unsigned e = buf[(s * NB + b) * CAPS + i];
      raw[tot + i] = e;
      atomicAdd(&hist[e >> 17], 1);
    }
    tot += c;
  }
  __syncthreads();
  if (t < 64) {
    int v = hist[t];
    int ex = v;
    #pragma unroll
    for (int off = 1; off < 64; off <<= 1) {
      int w = __shfl_up(ex, off);
      if ((t & 63) >= off) ex += w;
    }
    offs[t] = ex - v;
    starts[t] = ex - v;
  }
  __syncthreads();
  for (int i = t; i < tot; i += 256) {
    unsigned e = raw[i];
    int pos = atomicAdd(&offs[e >> 17], 1);
    sorted[pos] = e & 0x1FFFFu;
  }
  // stage [w2; ws] -> bf16 LDS (independent of sort; synced by phase-B barrier)
  #pragma unroll
  for (int i = 0; i < 16; ++i) {
    int j = t + i * 256;
    const float* srcp = (j < 2048) ? &w2[2 * j] : &wsw[2 * (j - 2048)];
    float2 v = *reinterpret_cast<const float2*>(srcp);
    reinterpret_cast<unsigned*>(Wss)[j] = pk2(v.x, v.y);
  }
  __syncthreads();
  // ---- phase B: gather-aggregate u into ts ----
  int lane = t & 63;
  int w = t >> 6;
  int half = lane >> 5;
  int c = lane & 31;
  for (int k = 0; k < 16; ++k) {
    int nl = w * 16 + k;
    int n = b * 64 + nl;
    if (n >= NN) break;
    int dg = hist[nl];
    int st = starts[nl];
    unsigned q = Qb32[n * 32 + c];
    float q0 = bf2f((ushort)(q & 0xFFFFu)), q1 = bf2f((ushort)(q >> 16));
    float a0 = 0.f, a1 = 0.f;
    int npair = (dg + 1) >> 1;
    #pragma unroll 2
    for (int p = 0; p < npair; ++p) {
      int e = 2 * p + half;
      if (e < dg) {
        unsigned src = sorted[st + e];
        unsigned pv = P32[src * 32 + c];
        a0 += fmaxf(bf2f((ushort)(pv & 0xFFFFu)) + q0, 0.f);
        a1 += fmaxf(bf2f((ushort)(pv >> 16)) + q1, 0.f);
      }
    }
    float o0 = __shfl(a0, c + 32);
    float o1 = __shfl(a1, c + 32);
    if (half == 0) {
      float inv = 1.f / (float)max(dg, 1);
      *reinterpret_cast<float2*>(&ts[nl * 66 + 2 * c]) =
          make_float2((a0 + o0) * inv, (a1 + o1) * inv);
    }
  }
  __syncthreads();
  // ---- phase C: out = u@w2 + x@ws + bs (+ b2 iff deg>0) ----
  int tr = t >> 4, tc = t & 15;
  float acc[4][4];
  #pragma unroll
  for (int i = 0; i < 4; ++i)
    #pragma unroll
    for (int j = 0; j < 4; ++j) acc[i][j] = 0.f;
  #pragma unroll 4
  for (int k = 0; k < 64; ++k) {
    float a0 = ts[(4 * tr + 0) * 66 + k];
    float a1 = ts[(4 * tr + 1) * 66 + k];
    float a2 = ts[(4 * tr + 2) * 66 + k];
    float a3 = ts[(4 * tr + 3) * 66 + k];
    uint2 wv = *reinterpret_cast<const uint2*>(&Wss[k * 64 + 4 * tc]);
    float w0 = bf2f((ushort)(wv.x & 0xFFFFu)), w1f = bf2f((ushort)(wv.x >> 16));
    float w2f = bf2f((ushort)(wv.y & 0xFFFFu)), w3 = bf2f((ushort)(wv.y >> 16));
    acc[0][0] = fmaf(a0, w0, acc[0][0]); acc[0][1] = fmaf(a0, w1f, acc[0][1]);
    acc[0][2] = fmaf(a0, w2f, acc[0][2]); acc[0][3] = fmaf(a0, w3, acc[0][3]);
    acc[1][0] = fmaf(a1, w0, acc[1][0]); acc[1][1] = fmaf(a1, w1f, acc[1][1]);
    acc[1][2] = fmaf(a1, w2f, acc[1][2]); acc[1][3] = fmaf(a1, w3, acc[1][3]);
    acc[2][0] = fmaf(a2, w0, acc[2][0]); acc[2][1] = fmaf(a2, w1f, acc[2][1]);
    acc[2][2] = fmaf(a2, w2f, acc[2][2]); acc[2][3] = fmaf(a2, w3, acc[2][3]);
    acc[3][0] = fmaf(a3, w0, acc[3][0]); acc[3][1] = fmaf(a3, w1f, acc[3][1]);
    acc[3][2] = fmaf(a3, w2f, acc[3][2]); acc[3][3] = fmaf(a3, w3, acc[3][3]);
  }
  __syncthreads();
  // restage x tile into ts
  int base = b * 64;
  #pragma unroll
  for (int i = 0; i < 4; ++i) {
    int idx4 = t + i * 256;
    int r = idx4 >> 4, cc = idx4 & 15;
    int grow = base + r;
    float4 v = make_float4(0.f, 0.f, 0.f, 0.f);
    if (grow < NN) v = reinterpret_cast<const float4*>(x)[grow * 16 + cc];
    float* p = &ts[r * 66 + cc * 4];
    *reinterpret_cast<float2*>(p) = make_float2(v.x, v.y);
    *reinterpret_cast<float2*>(p + 2) = make_float2(v.z, v.w);
  }
  __syncthreads();
  #pragma unroll 4
  for (int k = 0; k < 64; ++k) {
    float a0 = ts[(4 * tr + 0) * 66 + k];
    float a1 = ts[(4 * tr + 1) * 66 + k];
    float a2 = ts[(4 * tr + 2) * 66 + k];
    float a3 = ts[(4 * tr + 3) * 66 + k];
    uint2 wv = *reinterpret_cast<const uint2*>(&Wss[(64 + k) * 64 + 4 * tc]);
    float w0 = bf2f((ushort)(wv.x & 0xFFFFu)), w1f = bf2f((ushort)(wv.x >> 16));
    float w2f = bf2f((ushort)(wv.y & 0xFFFFu)), w3 = bf2f((ushort)(wv.y >> 16));
    acc[0][0] = fmaf(a0, w0, acc[0][0]); acc[0][1] = fmaf(a0, w1f, acc[0][1]);
    acc[0][2] = fmaf(a0, w2f, acc[0][2]); acc[0][3] = fmaf(a0, w3, acc[0][3]);
    acc[1][0] = fmaf(a1, w0, acc[1][0]); acc[1][1] = fmaf(a1, w1f, acc[1][1]);
    acc[1][2] = fmaf(a1, w2f, acc[1][2]); acc[1][3] = fmaf(a1, w3, acc[1][3]);
    acc[2][0] = fmaf(a2, w0, acc[2][0]); acc[2][1] = fmaf(a2, w1f, acc[2][1]);
    acc[2][2] = fmaf(a2, w2f, acc[2][2]); acc[2][3] = fmaf(a2, w3, acc[2][3]);
    acc[3][0] = fmaf(a3, w0, acc[3][0]); acc[3][1] = fmaf(a3, w1f, acc[3][1]);
    acc[3][2] = fmaf(a3, w2f, acc[3][2]); acc[3][3] = fmaf(a3, w3, acc[3][3]);
  }
  #pragma unroll
  for (int i = 0; i < 4; ++i) {
    int rl = 4 * tr + i;
    int row = base + rl;
    if (row < NN) {
      float bsc = (hist[rl] > 0) ? 1.f : 0.f;
      float4 o;
      o.x = acc[i][0] + bs[4 * tc + 0] + bsc * b2[4 * tc + 0];
      o.y = acc[i][1] + bs[4 * tc + 1] + bsc * b2[4 * tc + 1];
      o.z = acc[i][2] + bs[4 * tc + 2] + bsc * b2[4 * tc + 2];
      o.w = acc[i][3] + bs[4 * tc + 3] + bsc * b2[4 * tc + 3];
      *reinterpret_cast<float4*>(&out[row * 64 + 4 * tc]) = o;
    }
  }
}

extern "C" void kernel_launch(void* const* d_in, const int* in_sizes, int n_in,
                              void* d_out, int out_size, void* d_ws, size_t ws_size,
                              hipStream_t stream) {
  const float* x   = (const float*)d_in[0];
  const int*   ei  = (const int*)d_in[1];
  const float* w1  = (const float*)d_in[2];
  const float* b1  = (const float*)d_in[3];
  const float* w2  = (const float*)d_in[4];
  const float* b2  = (const float*)d_in[5];
  const float* wsw = (const float*)d_in[6];
  const float* bs  = (const float*)d_in[7];
  float* out = (float*)d_out;
  char* ws = (char*)d_ws;
  int* cnt      = (int*)(ws + OFF_CNT);
  unsigned* buf = (unsigned*)(ws + OFF_BUF);
  ushort* P     = (ushort*)(ws + OFF_P);
  ushort* Qb    = (ushort*)(ws + OFF_Q);

  hipMemsetAsync(cnt, 0, NSUB * NB * sizeof(int), stream);
  k_pre<<<NBIN + NLIN, 256, 0, stream>>>(ei, cnt, buf, x, w1, b1, P, Qb);
  k_aggfinal<<<NB, 256, 0, stream>>>(cnt, buf, (const unsigned*)P,
                                     (const unsigned*)Qb, x, w2, b2, wsw, bs, out);
}

// Round 4
// 270.462 us; speedup vs baseline: 1.4262x; 1.4262x over previous
//
#include <hip/hip_runtime.h>
#include <hip/hip_bf16.h>

#define NN 100000
#define EE 1600000
#define NB 1563          // ceil(NN/64) dst-buckets of 64 nodes
#define NSUB 8           // sub-buffers (~XCD) for write locality
#define CAPS 240         // capacity per (sub,bucket); lambda=128, ~10 sigma
#define NBIN (EE / 256)
#define NLIN ((NN + 63) / 64)

// workspace byte offsets (256-aligned)
#define OFF_CNT 0u                // NSUB*NB*4 = 50016
#define OFF_DEG 50176u            // NN*4 = 400000
#define OFF_BUF 450560u           // NSUB*NB*CAPS*4 = 12003840
#define OFF_P   12454400u         // NN*64*2 = 12800000 (bf16)
#define OFF_Q   25254400u         // NN*64*2
#define OFF_U   38054400u         // NN*64*2 (bf16)
// total 50854400 B ~= 48.5 MB

__device__ __forceinline__ ushort f2bf(float f) {
  unsigned u = __float_as_uint(f);
  unsigned r = (u + 0x7FFFu + ((u >> 16) & 1u)) >> 16;
  return (ushort)r;
}
__device__ __forceinline__ float bf2f(ushort h) {
  return __uint_as_float(((unsigned)h) << 16);
}
__device__ __forceinline__ unsigned pk2(float a, float b) {
  return (unsigned)f2bf(a) | ((unsigned)f2bf(b) << 16);
}

// ---------------- binning: append (src | ldst<<17) to dst-bucket --------------
__global__ void k_bin(const int* __restrict__ ei, int* __restrict__ cnt,
                      unsigned* __restrict__ buf) {
  int i = blockIdx.x * 256 + threadIdx.x;
  int s = ei[i];
  int d = ei[EE + i];
  int b = d >> 6;
  int sub = blockIdx.x & (NSUB - 1);
  int pos = atomicAdd(&cnt[sub * NB + b], 1);
  if (pos < CAPS)
    buf[(sub * NB + b) * CAPS + pos] = (unsigned)s | ((unsigned)(d & 63) << 17);
}

// ---------------- lin1: P = x@w1[:64], Qb = x@w1[64:] + b1 (bf16 out) ---------
__launch_bounds__(256)
__global__ void k_lin1(const float* __restrict__ x, const float* __restrict__ w1,
                       const float* __restrict__ b1, ushort* __restrict__ P,
                       ushort* __restrict__ Qb) {
  __shared__ ushort w1s[128 * 64];   // bf16 weights, 16 KB
  __shared__ float xs[64 * 66];      // fp32 x tile
  int t = threadIdx.x;
  int base = blockIdx.x * 64;
  #pragma unroll
  for (int i = 0; i < 16; ++i) {
    int j = t + i * 256;
    float2 v = *reinterpret_cast<const float2*>(&w1[2 * j]);
    reinterpret_cast<unsigned*>(w1s)[j] = pk2(v.x, v.y);
  }
  #pragma unroll
  for (int i = 0; i < 4; ++i) {
    int idx4 = t + i * 256;
    int r = idx4 >> 4, c = idx4 & 15;
    int grow = base + r;
    float4 v = make_float4(0.f, 0.f, 0.f, 0.f);
    if (grow < NN) v = reinterpret_cast<const float4*>(x)[grow * 16 + c];
    float* p = &xs[r * 66 + c * 4];
    *reinterpret_cast<float2*>(p) = make_float2(v.x, v.y);
    *reinterpret_cast<float2*>(p + 2) = make_float2(v.z, v.w);
  }
  __syncthreads();
  int tr = t >> 4, tc = t & 15;
  int half = tc >> 3;
  int c0 = (tc & 7) * 8;
  float acc[4][8];
  #pragma unroll
  for (int i = 0; i < 4; ++i)
    #pragma unroll
    for (int j = 0; j < 8; ++j) acc[i][j] = 0.f;
  #pragma unroll 4
  for (int k = 0; k < 64; ++k) {
    float a0 = xs[(4 * tr + 0) * 66 + k];
    float a1 = xs[(4 * tr + 1) * 66 + k];
    float a2 = xs[(4 * tr + 2) * 66 + k];
    float a3 = xs[(4 * tr + 3) * 66 + k];
    uint4 wv = *reinterpret_cast<const uint4*>(&w1s[(half * 64 + k) * 64 + c0]);
    float wf[8];
    wf[0] = bf2f((ushort)(wv.x & 0xFFFFu)); wf[1] = bf2f((ushort)(wv.x >> 16));
    wf[2] = bf2f((ushort)(wv.y & 0xFFFFu)); wf[3] = bf2f((ushort)(wv.y >> 16));
    wf[4] = bf2f((ushort)(wv.z & 0xFFFFu)); wf[5] = bf2f((ushort)(wv.z >> 16));
    wf[6] = bf2f((ushort)(wv.w & 0xFFFFu)); wf[7] = bf2f((ushort)(wv.w >> 16));
    #pragma unroll
    for (int j = 0; j < 8; ++j) {
      acc[0][j] = fmaf(a0, wf[j], acc[0][j]);
      acc[1][j] = fmaf(a1, wf[j], acc[1][j]);
      acc[2][j] = fmaf(a2, wf[j], acc[2][j]);
      acc[3][j] = fmaf(a3, wf[j], acc[3][j]);
    }
  }
  if (half) {
    #pragma unroll
    for (int j = 0; j < 8; ++j) {
      float bv = b1[c0 + j];
      #pragma unroll
      for (int i = 0; i < 4; ++i) acc[i][j] += bv;
    }
  }
  ushort* dstb = (half ? Qb : P);
  #pragma unroll
  for (int i = 0; i < 4; ++i) {
    int row = base + 4 * tr + i;
    if (row < NN) {
      uint4 o = make_uint4(pk2(acc[i][0], acc[i][1]), pk2(acc[i][2], acc[i][3]),
                           pk2(acc[i][4], acc[i][5]), pk2(acc[i][6], acc[i][7]));
      *reinterpret_cast<uint4*>(&dstb[row * 64 + c0]) = o;
    }
  }
}

// ---------------- agg: low-LDS bucket sort + 4-edge-wide gather ---------------
__launch_bounds__(256)
__global__ void k_agg(const int* __restrict__ cnt, const unsigned* __restrict__ buf,
                      const uint2* __restrict__ P2, const uint2* __restrict__ Q2,
                      ushort* __restrict__ U, int* __restrict__ deg) {
  __shared__ unsigned sorted[NSUB * CAPS];  // 7.5 KB
  __shared__ int hist[64], offs[64], starts[64];
  int b = blockIdx.x;
  int t = threadIdx.x;
  if (t < 64) hist[t] = 0;
  __syncthreads();
  int cs[NSUB];
  // pass 1: histogram (buf read 1)
  #pragma unroll
  for (int s = 0; s < NSUB; ++s) {
    cs[s] = min(cnt[s * NB + b], CAPS);
    for (int i = t; i < cs[s]; i += 256)
      atomicAdd(&hist[buf[(s * NB + b) * CAPS + i] >> 17], 1);
  }
  __syncthreads();
  if (t < 64) {
    int v = hist[t], ex = v;
    #pragma unroll
    for (int off = 1; off < 64; off <<= 1) {
      int w = __shfl_up(ex, off);
      if ((t & 63) >= off) ex += w;
    }
    offs[t] = ex - v;
    starts[t] = ex - v;
  }
  __syncthreads();
  // pass 2: scatter into sorted (buf read 2, L2-resident)
  #pragma unroll
  for (int s = 0; s < NSUB; ++s) {
    for (int i = t; i < cs[s]; i += 256) {
      unsigned e = buf[(s * NB + b) * CAPS + i];
      int pos = atomicAdd(&offs[e >> 17], 1);
      sorted[pos] = e & 0x1FFFFu;
    }
  }
  __syncthreads();
  // gather: wave handles 1 node, 4 edges x 16 lanes x uint2 per iteration
  int lane = t & 63;
  int w = t >> 6;
  int eg = lane >> 4;
  int c = lane & 15;
  for (int k = 0; k < 16; ++k) {
    int nl = w * 16 + k;
    int n = b * 64 + nl;
    if (n >= NN) break;
    int dg = hist[nl];
    int st = starts[nl];
    uint2 q = Q2[n * 16 + c];
    float q0 = bf2f((ushort)(q.x & 0xFFFFu)), q1 = bf2f((ushort)(q.x >> 16));
    float q2 = bf2f((ushort)(q.y & 0xFFFFu)), q3 = bf2f((ushort)(q.y >> 16));
    float a0 = 0.f, a1 = 0.f, a2 = 0.f, a3 = 0.f;
    int e = st + eg, eend = st + dg;
    while (e + 4 < eend) {
      unsigned s0 = sorted[e];
      unsigned s1 = sorted[e + 4];
      uint2 p0 = P2[s0 * 16 + c];
      uint2 p1 = P2[s1 * 16 + c];
      a0 += fmaxf(bf2f((ushort)(p0.x & 0xFFFFu)) + q0, 0.f);
      a1 += fmaxf(bf2f((ushort)(p0.x >> 16)) + q1, 0.f);
      a2 += fmaxf(bf2f((ushort)(p0.y & 0xFFFFu)) + q2, 0.f);
      a3 += fmaxf(bf2f((ushort)(p0.y >> 16)) + q3, 0.f);
      a0 += fmaxf(bf2f((ushort)(p1.x & 0xFFFFu)) + q0, 0.f);
      a1 += fmaxf(bf2f((ushort)(p1.x >> 16)) + q1, 0.f);
      a2 += fmaxf(bf2f((ushort)(p1.y & 0xFFFFu)) + q2, 0.f);
      a3 += fmaxf(bf2f((ushort)(p1.y >> 16)) + q3, 0.f);
      e += 8;
    }
    if (e < eend) {
      unsigned s0 = sorted[e];
      uint2 p0 = P2[s0 * 16 + c];
      a0 += fmaxf(bf2f((ushort)(p0.x & 0xFFFFu)) + q0, 0.f);
      a1 += fmaxf(bf2f((ushort)(p0.x >> 16)) + q1, 0.f);
      a2 += fmaxf(bf2f((ushort)(p0.y & 0xFFFFu)) + q2, 0.f);
      a3 += fmaxf(bf2f((ushort)(p0.y >> 16)) + q3, 0.f);
    }
    a0 += __shfl_xor(a0, 16); a0 += __shfl_xor(a0, 32);
    a1 += __shfl_xor(a1, 16); a1 += __shfl_xor(a1, 32);
    a2 += __shfl_xor(a2, 16); a2 += __shfl_xor(a2, 32);
    a3 += __shfl_xor(a3, 16); a3 += __shfl_xor(a3, 32);
    if (eg == 0) {
      float inv = 1.f / (float)max(dg, 1);
      reinterpret_cast<uint2*>(U)[n * 16 + c] =
          make_uint2(pk2(a0 * inv, a1 * inv), pk2(a2 * inv, a3 * inv));
    }
  }
  if (t < 64 && b * 64 + t < NN) deg[b * 64 + t] = hist[t];
}

// ---------------- final: out = u@w2 + x@ws + bs (+ b2 iff deg>0) -------------
__launch_bounds__(256)
__global__ void k_final(const float* __restrict__ x, const ushort* __restrict__ U,
                        const float* __restrict__ w2, const float* __restrict__ b2,
                        const float* __restrict__ wsw, const float* __restrict__ bs,
                        const int* __restrict__ deg, float* __restrict__ out) {
  __shared__ ushort Wss[128 * 64];  // bf16 [w2; ws], 16 KB
  __shared__ float ts[64 * 66];
  int t = threadIdx.x;
  int base = blockIdx.x * 64;
  #pragma unroll
  for (int i = 0; i < 16; ++i) {
    int j = t + i * 256;
    const float* srcp = (j < 2048) ? &w2[2 * j] : &wsw[2 * (j - 2048)];
    float2 v = *reinterpret_cast<const float2*>(srcp);
    reinterpret_cast<unsigned*>(Wss)[j] = pk2(v.x, v.y);
  }
  // stage U tile (bf16 -> fp32)
  #pragma unroll
  for (int i = 0; i < 4; ++i) {
    int idx = t + i * 256;
    int r = idx >> 4, c = idx & 15;
    int grow = base + r;
    uint2 v = make_uint2(0u, 0u);
    if (grow < NN) v = reinterpret_cast<const uint2*>(U)[grow * 16 + c];
    float* p = &ts[r * 66 + c * 4];
    p[0] = bf2f((ushort)(v.x & 0xFFFFu));
    p[1] = bf2f((ushort)(v.x >> 16));
    p[2] = bf2f((ushort)(v.y & 0xFFFFu));
    p[3] = bf2f((ushort)(v.y >> 16));
  }
  __syncthreads();
  int tr = t >> 4, tc = t & 15;
  float acc[4][4];
  #pragma unroll
  for (int i = 0; i < 4; ++i)
    #pragma unroll
    for (int j = 0; j < 4; ++j) acc[i][j] = 0.f;
  #pragma unroll 4
  for (int k = 0; k < 64; ++k) {
    float a0 = ts[(4 * tr + 0) * 66 + k];
    float a1 = ts[(4 * tr + 1) * 66 + k];
    float a2 = ts[(4 * tr + 2) * 66 + k];
    float a3 = ts[(4 * tr + 3) * 66 + k];
    uint2 wv = *reinterpret_cast<const uint2*>(&Wss[k * 64 + 4 * tc]);
    float w0 = bf2f((ushort)(wv.x & 0xFFFFu)), w1f = bf2f((ushort)(wv.x >> 16));
    float w2f = bf2f((ushort)(wv.y & 0xFFFFu)), w3 = bf2f((ushort)(wv.y >> 16));
    acc[0][0] = fmaf(a0, w0, acc[0][0]); acc[0][1] = fmaf(a0, w1f, acc[0][1]);
    acc[0][2] = fmaf(a0, w2f, acc[0][2]); acc[0][3] = fmaf(a0, w3, acc[0][3]);
    acc[1][0] = fmaf(a1, w0, acc[1][0]); acc[1][1] = fmaf(a1, w1f, acc[1][1]);
    acc[1][2] = fmaf(a1, w2f, acc[1][2]); acc[1][3] = fmaf(a1, w3, acc[1][3]);
    acc[2][0] = fmaf(a2, w0, acc[2][0]); acc[2][1] = fmaf(a2, w1f, acc[2][1]);
    acc[2][2] = fmaf(a2, w2f, acc[2][2]); acc[2][3] = fmaf(a2, w3, acc[2][3]);
    acc[3][0] = fmaf(a3, w0, acc[3][0]); acc[3][1] = fmaf(a3, w1f, acc[3][1]);
    acc[3][2] = fmaf(a3, w2f, acc[3][2]); acc[3][3] = fmaf(a3, w3, acc[3][3]);
  }
  __syncthreads();
  // restage x tile (fp32)
  #pragma unroll
  for (int i = 0; i < 4; ++i) {
    int idx4 = t + i * 256;
    int r = idx4 >> 4, cc = idx4 & 15;
    int grow = base + r;
    float4 v = make_float4(0.f, 0.f, 0.f, 0.f);
    if (grow < NN) v = reinterpret_cast<const float4*>(x)[grow * 16 + cc];
    float* p = &ts[r * 66 + cc * 4];
    *reinterpret_cast<float2*>(p) = make_float2(v.x, v.y);
    *reinterpret_cast<float2*>(p + 2) = make_float2(v.z, v.w);
  }
  __syncthreads();
  #pragma unroll 4
  for (int k = 0; k < 64; ++k) {
    float a0 = ts[(4 * tr + 0) * 66 + k];
    float a1 = ts[(4 * tr + 1) * 66 + k];
    float a2 = ts[(4 * tr + 2) * 66 + k];
    float a3 = ts[(4 * tr + 3) * 66 + k];
    uint2 wv = *reinterpret_cast<const uint2*>(&Wss[(64 + k) * 64 + 4 * tc]);
    float w0 = bf2f((ushort)(wv.x & 0xFFFFu)), w1f = bf2f((ushort)(wv.x >> 16));
    float w2f = bf2f((ushort)(wv.y & 0xFFFFu)), w3 = bf2f((ushort)(wv.y >> 16));
    acc[0][0] = fmaf(a0, w0, acc[0][0]); acc[0][1] = fmaf(a0, w1f, acc[0][1]);
    acc[0][2] = fmaf(a0, w2f, acc[0][2]); acc[0][3] = fmaf(a0, w3, acc[0][3]);
    acc[1][0] = fmaf(a1, w0, acc[1][0]); acc[1][1] = fmaf(a1, w1f, acc[1][1]);
    acc[1][2] = fmaf(a1, w2f, acc[1][2]); acc[1][3] = fmaf(a1, w3, acc[1][3]);
    acc[2][0] = fmaf(a2, w0, acc[2][0]); acc[2][1] = fmaf(a2, w1f, acc[2][1]);
    acc[2][2] = fmaf(a2, w2f, acc[2][2]); acc[2][3] = fmaf(a2, w3, acc[2][3]);
    acc[3][0] = fmaf(a3, w0, acc[3][0]); acc[3][1] = fmaf(a3, w1f, acc[3][1]);
    acc[3][2] = fmaf(a3, w2f, acc[3][2]); acc[3][3] = fmaf(a3, w3, acc[3][3]);
  }
  #pragma unroll
  for (int i = 0; i < 4; ++i) {
    int rl = 4 * tr + i;
    int row = base + rl;
    if (row < NN) {
      float bsc = (deg[row] > 0) ? 1.f : 0.f;
      float4 o;
      o.x = acc[i][0] + bs[4 * tc + 0] + bsc * b2[4 * tc + 0];
      o.y = acc[i][1] + bs[4 * tc + 1] + bsc * b2[4 * tc + 1];
      o.z = acc[i][2] + bs[4 * tc + 2] + bsc * b2[4 * tc + 2];
      o.w = acc[i][3] + bs[4 * tc + 3] + bsc * b2[4 * tc + 3];
      *reinterpret_cast<float4*>(&out[row * 64 + 4 * tc]) = o;
    }
  }
}

extern "C" void kernel_launch(void* const* d_in, const int* in_sizes, int n_in,
                              void* d_out, int out_size, void* d_ws, size_t ws_size,
                              hipStream_t stream) {
  const float* x   = (const float*)d_in[0];
  const int*   ei  = (const int*)d_in[1];
  const float* w1  = (const float*)d_in[2];
  const float* b1  = (const float*)d_in[3];
  const float* w2  = (const float*)d_in[4];
  const float* b2  = (const float*)d_in[5];
  const float* wsw = (const float*)d_in[6];
  const float* bs  = (const float*)d_in[7];
  float* out = (float*)d_out;
  char* ws = (char*)d_ws;
  int* cnt      = (int*)(ws + OFF_CNT);
  int* deg      = (int*)(ws + OFF_DEG);
  unsigned* buf = (unsigned*)(ws + OFF_BUF);
  ushort* P     = (ushort*)(ws + OFF_P);
  ushort* Qb    = (ushort*)(ws + OFF_Q);
  ushort* U     = (ushort*)(ws + OFF_U);

  hipMemsetAsync(cnt, 0, NSUB * NB * sizeof(int), stream);
  k_bin<<<NBIN, 256, 0, stream>>>(ei, cnt, buf);
  k_lin1<<<NLIN, 256, 0, stream>>>(x, w1, b1, P, Qb);
  k_agg<<<NB, 256, 0, stream>>>(cnt, buf, (const uint2*)P, (const uint2*)Qb, U, deg);
  k_final<<<NLIN, 256, 0, stream>>>(x, U, w2, b2, wsw, bs, deg, out);
}

// Round 5
// 229.922 us; speedup vs baseline: 1.6777x; 1.1763x over previous
//
#include <hip/hip_runtime.h>
#include <hip/hip_bf16.h>

#define NN 100000
#define EE 1600000
#define NB 1563          // fine dst-buckets of 64 nodes
#define NSUB 8           // sub-buffers per fine bucket (written by binB slice j)
#define CAPS 240         // capacity per (sub,fine); mean 128
#define NBC 98           // coarse buckets of 1024 nodes
#define CAPC 17408       // per-coarse capacity; mean 16384, +8 sigma
#define CHA 2048         // edges per binA block
#define NBLA 782         // ceil(EE/CHA)
#define NLIN ((NN + 63) / 64)

// workspace byte offsets (256-aligned)
#define OFF_CNT 0u                // cnt NSUB*NB*4 + ccnt NBC*4 = 50408
#define OFF_DEG 50432u            // NN*4 = 400000
#define OFF_BUF 450560u           // NSUB*NB*CAPS*4 = 12003840
#define OFF_P   12454400u         // NN*64*2 (bf16)
#define OFF_Q   25254400u         // NN*64*2
#define OFF_U   38054400u         // NN*64*2 (bf16); cbuf (6.8 MB) aliases this
// total 50854400 B

__device__ __forceinline__ ushort f2bf(float f) {
  unsigned u = __float_as_uint(f);
  unsigned r = (u + 0x7FFFu + ((u >> 16) & 1u)) >> 16;
  return (ushort)r;
}
__device__ __forceinline__ float bf2f(ushort h) {
  return __uint_as_float(((unsigned)h) << 16);
}
__device__ __forceinline__ unsigned pk2(float a, float b) {
  return (unsigned)f2bf(a) | ((unsigned)f2bf(b) << 16);
}

// -------- binA: LDS counting-sort 2048-edge chunks into 98 coarse buckets ----
// entry: src(17b) | (d & 1023) << 17   (bits 17..26)
__launch_bounds__(256)
__global__ void k_binA(const int* __restrict__ ei, int* __restrict__ ccnt,
                       unsigned* __restrict__ cbuf) {
  __shared__ int hist[NBC], offs[NBC], starts[NBC], gbase[NBC];
  __shared__ int wtot[4];
  __shared__ unsigned sorted[CHA];
  __shared__ ushort bkt[CHA];
  int t = threadIdx.x;
  if (t < NBC) hist[t] = 0;
  __syncthreads();
  unsigned ent[8];
  int cb[8];
  int e0 = blockIdx.x * CHA;
  #pragma unroll
  for (int it = 0; it < 8; ++it) {
    int e = e0 + t + it * 256;
    cb[it] = -1;
    if (e < EE) {
      int s = ei[e], d = ei[EE + e];
      ent[it] = (unsigned)s | ((unsigned)(d & 1023) << 17);
      cb[it] = d >> 10;
      atomicAdd(&hist[cb[it]], 1);
    }
  }
  __syncthreads();
  {  // exclusive scan of hist[0..NBC)
    int v = (t < NBC) ? hist[t] : 0;
    int x = v;
    #pragma unroll
    for (int off = 1; off < 64; off <<= 1) {
      int w = __shfl_up(x, off);
      if ((t & 63) >= off) x += w;
    }
    if ((t & 63) == 63) wtot[t >> 6] = x;
    __syncthreads();
    int pre = 0;
    #pragma unroll
    for (int w = 0; w < 4; ++w)
      if (w < (t >> 6)) pre += wtot[w];
    if (t < NBC) { offs[t] = pre + x - v; starts[t] = pre + x - v; }
  }
  __syncthreads();
  #pragma unroll
  for (int it = 0; it < 8; ++it) {
    if (cb[it] >= 0) {
      int pos = atomicAdd(&offs[cb[it]], 1);
      sorted[pos] = ent[it];
      bkt[pos] = (ushort)cb[it];
    }
  }
  __syncthreads();
  if (t < NBC) {
    int c = hist[t];
    gbase[t] = (c > 0) ? atomicAdd(&ccnt[t], c) : 0;
  }
  __syncthreads();
  int tot = min(EE - e0, CHA);
  for (int i = t; i < tot; i += 256) {
    int b = bkt[i];
    int dst = gbase[b] + (i - starts[b]);
    if (dst < CAPC) cbuf[b * CAPC + dst] = sorted[i];
  }
}

// -------- binB: refine coarse slice into 16 fine buckets (coalesced flush) ---
// consumes entry27; emits fine entry: src | (d&63)<<17 into cnt/buf layout
__launch_bounds__(256)
__global__ void k_binB(const int* __restrict__ ccnt, const unsigned* __restrict__ cbuf,
                       int* __restrict__ cnt, unsigned* __restrict__ buf) {
  __shared__ int hist[16], offs[16], starts[16], gbase[16];
  __shared__ unsigned sorted[2304];
  int t = threadIdx.x;
  int cb = blockIdx.x >> 3;
  int j  = blockIdx.x & 7;
  if (t < 16) hist[t] = 0;
  __syncthreads();
  int tot = min(ccnt[cb], CAPC);
  int beg = (tot * j) >> 3;
  int end = (tot * (j + 1)) >> 3;
  int n = end - beg;
  unsigned ent[9];
  int fb[9];
  #pragma unroll
  for (int it = 0; it < 9; ++it) {
    int i = t + it * 256;
    fb[it] = -1;
    if (i < n) {
      unsigned e = cbuf[cb * CAPC + beg + i];
      ent[it] = e;
      fb[it] = (int)(e >> 23);
      atomicAdd(&hist[fb[it]], 1);
    }
  }
  __syncthreads();
  if (t < 16) {
    int v = hist[t], x = v;
    #pragma unroll
    for (int off = 1; off < 16; off <<= 1) {
      int w = __shfl_up(x, off);
      if (t >= off) x += w;
    }
    offs[t] = x - v;
    starts[t] = x - v;
  }
  __syncthreads();
  #pragma unroll
  for (int it = 0; it < 9; ++it) {
    if (fb[it] >= 0) {
      int pos = atomicAdd(&offs[fb[it]], 1);
      sorted[pos] = ent[it];
    }
  }
  __syncthreads();
  if (t < 16) {
    int c = hist[t];
    int fbg = cb * 16 + t;
    gbase[t] = (c > 0 && fbg < NB) ? atomicAdd(&cnt[j * NB + fbg], c) : 0;
  }
  __syncthreads();
  for (int i = t; i < n; i += 256) {
    unsigned e = sorted[i];
    int b = (int)(e >> 23);
    int fbg = cb * 16 + b;
    int dst = gbase[b] + (i - starts[b]);
    if (dst < CAPS && fbg < NB)
      buf[(unsigned)(j * NB + fbg) * CAPS + dst] = e & 0x7FFFFFu;
  }
}

// ---------------- lin1: P = x@w1[:64], Qb = x@w1[64:] + b1 (bf16 out) ---------
__launch_bounds__(256)
__global__ void k_lin1(const float* __restrict__ x, const float* __restrict__ w1,
                       const float* __restrict__ b1, ushort* __restrict__ P,
                       ushort* __restrict__ Qb) {
  __shared__ float w1s[128 * 64];   // fp32 weights, 32 KB
  __shared__ float xs[64 * 66];
  int t = threadIdx.x;
  int base = blockIdx.x * 64;
  #pragma unroll
  for (int i = 0; i < 8; ++i) {
    int idx4 = t + i * 256;
    reinterpret_cast<float4*>(w1s)[idx4] = reinterpret_cast<const float4*>(w1)[idx4];
  }
  #pragma unroll
  for (int i = 0; i < 4; ++i) {
    int idx4 = t + i * 256;
    int r = idx4 >> 4, c = idx4 & 15;
    int grow = base + r;
    float4 v = make_float4(0.f, 0.f, 0.f, 0.f);
    if (grow < NN) v = reinterpret_cast<const float4*>(x)[grow * 16 + c];
    float* p = &xs[r * 66 + c * 4];
    *reinterpret_cast<float2*>(p) = make_float2(v.x, v.y);
    *reinterpret_cast<float2*>(p + 2) = make_float2(v.z, v.w);
  }
  __syncthreads();
  int tr = t >> 4, tc = t & 15;
  int half = tc >> 3;
  int c0 = (tc & 7) * 8;
  float acc[4][8];
  #pragma unroll
  for (int i = 0; i < 4; ++i)
    #pragma unroll
    for (int j = 0; j < 8; ++j) acc[i][j] = 0.f;
  #pragma unroll 4
  for (int k = 0; k < 64; ++k) {
    float a0 = xs[(4 * tr + 0) * 66 + k];
    float a1 = xs[(4 * tr + 1) * 66 + k];
    float a2 = xs[(4 * tr + 2) * 66 + k];
    float a3 = xs[(4 * tr + 3) * 66 + k];
    const float* bp = &w1s[(half * 64 + k) * 64 + c0];
    float4 w0 = *reinterpret_cast<const float4*>(bp);
    float4 w1v = *reinterpret_cast<const float4*>(bp + 4);
    float wf[8] = {w0.x, w0.y, w0.z, w0.w, w1v.x, w1v.y, w1v.z, w1v.w};
    #pragma unroll
    for (int j = 0; j < 8; ++j) {
      acc[0][j] = fmaf(a0, wf[j], acc[0][j]);
      acc[1][j] = fmaf(a1, wf[j], acc[1][j]);
      acc[2][j] = fmaf(a2, wf[j], acc[2][j]);
      acc[3][j] = fmaf(a3, wf[j], acc[3][j]);
    }
  }
  if (half) {
    #pragma unroll
    for (int j = 0; j < 8; ++j) {
      float bv = b1[c0 + j];
      #pragma unroll
      for (int i = 0; i < 4; ++i) acc[i][j] += bv;
    }
  }
  ushort* dstb = (half ? Qb : P);
  #pragma unroll
  for (int i = 0; i < 4; ++i) {
    int row = base + 4 * tr + i;
    if (row < NN) {
      uint4 o = make_uint4(pk2(acc[i][0], acc[i][1]), pk2(acc[i][2], acc[i][3]),
                           pk2(acc[i][4], acc[i][5]), pk2(acc[i][6], acc[i][7]));
      *reinterpret_cast<uint4*>(&dstb[row * 64 + c0]) = o;
    }
  }
}

// ---------------- agg: low-LDS bucket sort + 4-edge-wide gather ---------------
__launch_bounds__(256)
__global__ void k_agg(const int* __restrict__ cnt, const unsigned* __restrict__ buf,
                      const uint2* __restrict__ P2, const uint2* __restrict__ Q2,
                      ushort* __restrict__ U, int* __restrict__ deg) {
  __shared__ unsigned sorted[NSUB * CAPS];
  __shared__ int hist[64], offs[64], starts[64];
  int b = blockIdx.x;
  int t = threadIdx.x;
  if (t < 64) hist[t] = 0;
  __syncthreads();
  int cs[NSUB];
  #pragma unroll
  for (int s = 0; s < NSUB; ++s) {
    cs[s] = min(cnt[s * NB + b], CAPS);
    for (int i = t; i < cs[s]; i += 256)
      atomicAdd(&hist[buf[(s * NB + b) * CAPS + i] >> 17], 1);
  }
  __syncthreads();
  if (t < 64) {
    int v = hist[t], ex = v;
    #pragma unroll
    for (int off = 1; off < 64; off <<= 1) {
      int w = __shfl_up(ex, off);
      if ((t & 63) >= off) ex += w;
    }
    offs[t] = ex - v;
    starts[t] = ex - v;
  }
  __syncthreads();
  #pragma unroll
  for (int s = 0; s < NSUB; ++s) {
    for (int i = t; i < cs[s]; i += 256) {
      unsigned e = buf[(s * NB + b) * CAPS + i];
      int pos = atomicAdd(&offs[e >> 17], 1);
      sorted[pos] = e & 0x1FFFFu;
    }
  }
  __syncthreads();
  int lane = t & 63;
  int w = t >> 6;
  int eg = lane >> 4;
  int c = lane & 15;
  for (int k = 0; k < 16; ++k) {
    int nl = w * 16 + k;
    int n = b * 64 + nl;
    if (n >= NN) break;
    int dg = hist[nl];
    int st = starts[nl];
    uint2 q = Q2[n * 16 + c];
    float q0 = bf2f((ushort)(q.x & 0xFFFFu)), q1 = bf2f((ushort)(q.x >> 16));
    float q2 = bf2f((ushort)(q.y & 0xFFFFu)), q3 = bf2f((ushort)(q.y >> 16));
    float a0 = 0.f, a1 = 0.f, a2 = 0.f, a3 = 0.f;
    int e = st + eg, eend = st + dg;
    while (e + 4 < eend) {
      unsigned s0 = sorted[e];
      unsigned s1 = sorted[e + 4];
      uint2 p0 = P2[s0 * 16 + c];
      uint2 p1 = P2[s1 * 16 + c];
      a0 += fmaxf(bf2f((ushort)(p0.x & 0xFFFFu)) + q0, 0.f);
      a1 += fmaxf(bf2f((ushort)(p0.x >> 16)) + q1, 0.f);
      a2 += fmaxf(bf2f((ushort)(p0.y & 0xFFFFu)) + q2, 0.f);
      a3 += fmaxf(bf2f((ushort)(p0.y >> 16)) + q3, 0.f);
      a0 += fmaxf(bf2f((ushort)(p1.x & 0xFFFFu)) + q0, 0.f);
      a1 += fmaxf(bf2f((ushort)(p1.x >> 16)) + q1, 0.f);
      a2 += fmaxf(bf2f((ushort)(p1.y & 0xFFFFu)) + q2, 0.f);
      a3 += fmaxf(bf2f((ushort)(p1.y >> 16)) + q3, 0.f);
      e += 8;
    }
    if (e < eend) {
      unsigned s0 = sorted[e];
      uint2 p0 = P2[s0 * 16 + c];
      a0 += fmaxf(bf2f((ushort)(p0.x & 0xFFFFu)) + q0, 0.f);
      a1 += fmaxf(bf2f((ushort)(p0.x >> 16)) + q1, 0.f);
      a2 += fmaxf(bf2f((ushort)(p0.y & 0xFFFFu)) + q2, 0.f);
      a3 += fmaxf(bf2f((ushort)(p0.y >> 16)) + q3, 0.f);
    }
    a0 += __shfl_xor(a0, 16); a0 += __shfl_xor(a0, 32);
    a1 += __shfl_xor(a1, 16); a1 += __shfl_xor(a1, 32);
    a2 += __shfl_xor(a2, 16); a2 += __shfl_xor(a2, 32);
    a3 += __shfl_xor(a3, 16); a3 += __shfl_xor(a3, 32);
    if (eg == 0) {
      float inv = 1.f / (float)max(dg, 1);
      reinterpret_cast<uint2*>(U)[n * 16 + c] =
          make_uint2(pk2(a0 * inv, a1 * inv), pk2(a2 * inv, a3 * inv));
    }
  }
  if (t < 64 && b * 64 + t < NN) deg[b * 64 + t] = hist[t];
}

// ---------------- final: out = u@w2 + x@ws + bs (+ b2 iff deg>0) -------------
__launch_bounds__(256)
__global__ void k_final(const float* __restrict__ x, const ushort* __restrict__ U,
                        const float* __restrict__ w2, const float* __restrict__ b2,
                        const float* __restrict__ wsw, const float* __restrict__ bs,
                        const int* __restrict__ deg, float* __restrict__ out) {
  __shared__ float Wss[128 * 64];  // fp32 [w2; ws], 32 KB
  __shared__ float ts[64 * 66];
  int t = threadIdx.x;
  int base = blockIdx.x * 64;
  #pragma unroll
  for (int i = 0; i < 4; ++i) {
    int idx4 = t + i * 256;
    reinterpret_cast<float4*>(Wss)[idx4] = reinterpret_cast<const float4*>(w2)[idx4];
    reinterpret_cast<float4*>(Wss)[idx4 + 1024] = reinterpret_cast<const float4*>(wsw)[idx4];
  }
  #pragma unroll
  for (int i = 0; i < 4; ++i) {
    int idx = t + i * 256;
    int r = idx >> 4, c = idx & 15;
    int grow = base + r;
    uint2 v = make_uint2(0u, 0u);
    if (grow < NN) v = reinterpret_cast<const uint2*>(U)[grow * 16 + c];
    float* p = &ts[r * 66 + c * 4];
    p[0] = bf2f((ushort)(v.x & 0xFFFFu));
    p[1] = bf2f((ushort)(v.x >> 16));
    p[2] = bf2f((ushort)(v.y & 0xFFFFu));
    p[3] = bf2f((ushort)(v.y >> 16));
  }
  __syncthreads();
  int tr = t >> 4, tc = t & 15;
  float acc[4][4];
  #pragma unroll
  for (int i = 0; i < 4; ++i)
    #pragma unroll
    for (int j = 0; j < 4; ++j) acc[i][j] = 0.f;
  #pragma unroll 4
  for (int k = 0; k < 64; ++k) {
    float a0 = ts[(4 * tr + 0) * 66 + k];
    float a1 = ts[(4 * tr + 1) * 66 + k];
    float a2 = ts[(4 * tr + 2) * 66 + k];
    float a3 = ts[(4 * tr + 3) * 66 + k];
    float4 wv = *reinterpret_cast<const float4*>(&Wss[k * 64 + 4 * tc]);
    acc[0][0] = fmaf(a0, wv.x, acc[0][0]); acc[0][1] = fmaf(a0, wv.y, acc[0][1]);
    acc[0][2] = fmaf(a0, wv.z, acc[0][2]); acc[0][3] = fmaf(a0, wv.w, acc[0][3]);
    acc[1][0] = fmaf(a1, wv.x, acc[1][0]); acc[1][1] = fmaf(a1, wv.y, acc[1][1]);
    acc[1][2] = fmaf(a1, wv.z, acc[1][2]); acc[1][3] = fmaf(a1, wv.w, acc[1][3]);
    acc[2][0] = fmaf(a2, wv.x, acc[2][0]); acc[2][1] = fmaf(a2, wv.y, acc[2][1]);
    acc[2][2] = fmaf(a2, wv.z, acc[2][2]); acc[2][3] = fmaf(a2, wv.w, acc[2][3]);
    acc[3][0] = fmaf(a3, wv.x, acc[3][0]); acc[3][1] = fmaf(a3, wv.y, acc[3][1]);
    acc[3][2] = fmaf(a3, wv.z, acc[3][2]); acc[3][3] = fmaf(a3, wv.w, acc[3][3]);
  }
  __syncthreads();
  #pragma unroll
  for (int i = 0; i < 4; ++i) {
    int idx4 = t + i * 256;
    int r = idx4 >> 4, cc = idx4 & 15;
    int grow = base + r;
    float4 v = make_float4(0.f, 0.f, 0.f, 0.f);
    if (grow < NN) v = reinterpret_cast<const float4*>(x)[grow * 16 + cc];
    float* p = &ts[r * 66 + cc * 4];
    *reinterpret_cast<float2*>(p) = make_float2(v.x, v.y);
    *reinterpret_cast<float2*>(p + 2) = make_float2(v.z, v.w);
  }
  __syncthreads();
  #pragma unroll 4
  for (int k = 0; k < 64; ++k) {
    float a0 = ts[(4 * tr + 0) * 66 + k];
    float a1 = ts[(4 * tr + 1) * 66 + k];
    float a2 = ts[(4 * tr + 2) * 66 + k];
    float a3 = ts[(4 * tr + 3) * 66 + k];
    float4 wv = *reinterpret_cast<const float4*>(&Wss[(64 + k) * 64 + 4 * tc]);
    acc[0][0] = fmaf(a0, wv.x, acc[0][0]); acc[0][1] = fmaf(a0, wv.y, acc[0][1]);
    acc[0][2] = fmaf(a0, wv.z, acc[0][2]); acc[0][3] = fmaf(a0, wv.w, acc[0][3]);
    acc[1][0] = fmaf(a1, wv.x, acc[1][0]); acc[1][1] = fmaf(a1, wv.y, acc[1][1]);
    acc[1][2] = fmaf(a1, wv.z, acc[1][2]); acc[1][3] = fmaf(a1, wv.w, acc[1][3]);
    acc[2][0] = fmaf(a2, wv.x, acc[2][0]); acc[2][1] = fmaf(a2, wv.y, acc[2][1]);
    acc[2][2] = fmaf(a2, wv.z, acc[2][2]); acc[2][3] = fmaf(a2, wv.w, acc[2][3]);
    acc[3][0] = fmaf(a3, wv.x, acc[3][0]); acc[3][1] = fmaf(a3, wv.y, acc[3][1]);
    acc[3][2] = fmaf(a3, wv.z, acc[3][2]); acc[3][3] = fmaf(a3, wv.w, acc[3][3]);
  }
  #pragma unroll
  for (int i = 0; i < 4; ++i) {
    int rl = 4 * tr + i;
    int row = base + rl;
    if (row < NN) {
      float bsc = (deg[row] > 0) ? 1.f : 0.f;
      float4 o;
      o.x = acc[i][0] + bs[4 * tc + 0] + bsc * b2[4 * tc + 0];
      o.y = acc[i][1] + bs[4 * tc + 1] + bsc * b2[4 * tc + 1];
      o.z = acc[i][2] + bs[4 * tc + 2] + bsc * b2[4 * tc + 2];
      o.w = acc[i][3] + bs[4 * tc + 3] + bsc * b2[4 * tc + 3];
      *reinterpret_cast<float4*>(&out[row * 64 + 4 * tc]) = o;
    }
  }
}

extern "C" void kernel_launch(void* const* d_in, const int* in_sizes, int n_in,
                              void* d_out, int out_size, void* d_ws, size_t ws_size,
                              hipStream_t stream) {
  const float* x   = (const float*)d_in[0];
  const int*   ei  = (const int*)d_in[1];
  const float* w1  = (const float*)d_in[2];
  const float* b1  = (const float*)d_in[3];
  const float* w2  = (const float*)d_in[4];
  const float* b2  = (const float*)d_in[5];
  const float* wsw = (const float*)d_in[6];
  const float* bs  = (const float*)d_in[7];
  float* out = (float*)d_out;
  char* ws = (char*)d_ws;
  int* cnt       = (int*)(ws + OFF_CNT);
  int* ccnt      = cnt + NSUB * NB;
  int* deg       = (int*)(ws + OFF_DEG);
  unsigned* buf  = (unsigned*)(ws + OFF_BUF);
  ushort* P      = (ushort*)(ws + OFF_P);
  ushort* Qb     = (ushort*)(ws + OFF_Q);
  ushort* U      = (ushort*)(ws + OFF_U);
  unsigned* cbuf = (unsigned*)(ws + OFF_U);  // aliases U: consumed before U written

  hipMemsetAsync(cnt, 0, (NSUB * NB + NBC) * sizeof(int), stream);
  k_binA<<<NBLA, 256, 0, stream>>>(ei, ccnt, cbuf);
  k_binB<<<NBC * 8, 256, 0, stream>>>(ccnt, cbuf, cnt, buf);
  k_lin1<<<NLIN, 256, 0, stream>>>(x, w1, b1, P, Qb);
  k_agg<<<NB, 256, 0, stream>>>(cnt, buf, (const uint2*)P, (const uint2*)Qb, U, deg);
  k_final<<<NLIN, 256, 0, stream>>>(x, U, w2, b2, wsw, bs, deg, out);
}